// Round 7
// baseline (731.715 us; speedup 1.0000x reference)
//
#include <hip/hip_runtime.h>
#include <hip/hip_bf16.h>

#define C 128
#define L 16384
#define B 8
#define MID 32
#define NBL (B * L)

typedef unsigned short ushort_t;
typedef __attribute__((ext_vector_type(8))) short s8v;   // 8 bf16
typedef __attribute__((ext_vector_type(4))) float f4v;   // 4 fp32
typedef __attribute__((ext_vector_type(8))) float f8v;   // 8 fp32

__device__ __forceinline__ unsigned short f2bf(float f) {
    union { float f; unsigned int u; } a; a.f = f;
    unsigned int u = a.u;
    return (unsigned short)((u + 0x7fffu + ((u >> 16) & 1u)) >> 16);
}

// value-style helpers: no address-taken locals
__device__ __forceinline__ f8v unp8(s8v v) {
    f8v f;
#pragma unroll
    for (int j = 0; j < 8; j++) f[j] = __uint_as_float(((unsigned int)(unsigned short)v[j]) << 16);
    return f;
}

__device__ __forceinline__ s8v pk8(f8v f) {
    s8v v;
#pragma unroll
    for (int j = 0; j < 8; j++) v[j] = (short)f2bf(f[j]);
    return v;
}

__device__ __forceinline__ f8v ldf8(const float* p) {
    float4 a = *(const float4*)p;
    float4 b = *(const float4*)(p + 4);
    f8v f;
    f[0] = a.x; f[1] = a.y; f[2] = a.z; f[3] = a.w;
    f[4] = b.x; f[5] = b.y; f[6] = b.z; f[7] = b.w;
    return f;
}

// fragment-order index for staged weights: slot in [0,13), o = out channel row, w = col within slot's 32
__device__ __forceinline__ int widx(int slot, int o, int w) {
    return ((slot * 8 + (o >> 4)) * 64 + (w >> 3) * 16 + (o & 15)) * 8 + (w & 7);
}

// ------------------------------------------------ k_cvt: x fp32 [b][c][l] -> xb bf16 [b][l][c], + gap sums
// Coalesced reads: 8 passes of 16 c-rows x 64 l floats, lane-contiguous float4.
__global__ __launch_bounds__(256) void k_cvt(const float* __restrict__ x,
                                             ushort_t* __restrict__ xb,
                                             float* __restrict__ gap) {
    __shared__ float xs[64][129];             // [l][c]
    const int bid = blockIdx.x;
    const int b = bid >> 8;
    const int l0 = (bid & 255) * 64;
    const int tid = threadIdx.x;
    const int rr = tid >> 4;                  // row within pass (0..15)
    const int col = (tid & 15) * 4;           // l within tile (0..60)
#pragma unroll
    for (int pass = 0; pass < 8; pass++) {
        const int c = pass * 16 + rr;
        float4 v = *(const float4*)(x + ((size_t)(b * C + c)) * L + l0 + col);
        xs[col + 0][c] = v.x; xs[col + 1][c] = v.y;
        xs[col + 2][c] = v.z; xs[col + 3][c] = v.w;
    }
    __syncthreads();
    // gap partial sums (from LDS; 2-way bank aliasing = free)
    {
        const int c = tid >> 1, h = tid & 1;
        float s = 0.f;
#pragma unroll
        for (int k = 0; k < 32; k++) s += xs[h * 32 + k][c];
        s += __shfl_xor(s, 1);
        if (h == 0) atomicAdd(&gap[b * C + c], s);
    }
    // pack + coalesced write of [l][c] bf16
    const int l = tid & 63, quarter = tid >> 6, cb = quarter * 32;
    union { ushort_t hh[32]; uint4 qv[4]; } u;
#pragma unroll
    for (int k = 0; k < 32; k++) u.hh[k] = f2bf(xs[l][cb + k]);
    uint4* dst = (uint4*)(xb + ((size_t)(b * L + l0 + l)) * C + cb);
#pragma unroll
    for (int k = 0; k < 4; k++) dst[k] = u.qv[k];
}

// ------------------------------------------------ k_prep: merged weight-compose (bid<128) + per-batch gap work (bid>=128)
__global__ __launch_bounds__(128) void k_prep(const float* __restrict__ Win,
                                              const float* __restrict__ Wproj,
                                              const float* __restrict__ Wout,
                                              const float* __restrict__ w2,
                                              const float* __restrict__ b2,
                                              const float* __restrict__ wds,
                                              const float* __restrict__ gap,
                                              const float* __restrict__ w1,
                                              const float* __restrict__ Wco,
                                              const float* __restrict__ wcd,
                                              const float* __restrict__ Wci,
                                              ushort_t* __restrict__ Wf,
                                              float* __restrict__ bp,
                                              float* __restrict__ a,
                                              float* __restrict__ pv) {
    const int bid = blockIdx.x;
    const int c = threadIdx.x;
    if (bid < 128) {
        const int o = bid;
        __shared__ float pr[C];
        __shared__ float wct[C];
        pr[c] = Wproj[o * C + c];
        __syncthreads();
        {
            float s = 0.f;
            for (int k = 0; k < C; k++) s = fmaf(pr[k], Wout[k * C + c], s);
            wct[c] = s;
        }
        __syncthreads();
        float a1 = 0.f, as = 0.f;
        for (int cc = 0; cc < C; cc++) {
            float w = wct[cc];
            float win = Win[cc * C + c];
            a1 = fmaf(w * wds[3 * cc + 1], win, a1);
            as = fmaf(w * (0.25f * (wds[3 * cc] + wds[3 * cc + 2])), win, as);
        }
        const int slot = c >> 5, wi = c & 31;
        Wf[widx(slot, o, wi)] = f2bf(a1);
        Wf[widx(4 + slot, o, wi)] = f2bf(as);
        Wf[widx(8 + slot, o, wi)] = f2bf(pr[c]);
        if (c < MID) {
            float s2 = 0.f;
            for (int k = 0; k < C; k++) s2 = fmaf(pr[k], w2[k * MID + c], s2);
            Wf[widx(12, o, c)] = f2bf(s2);
        }
        if (c == 0) {
            float s3 = 0.f;
            for (int k = 0; k < C; k++) s3 = fmaf(pr[k], b2[k], s3);
            bp[o] = s3;
        }
    } else {
        const int b = bid - 128;
        __shared__ float gl[C];
        __shared__ float red[C];
        __shared__ float gws[C];
        float v = gap[b * C + c] * (1.f / (float)L);
        red[c] = v * v;
        __syncthreads();
        for (int w = 64; w > 0; w >>= 1) {
            if (c < w) red[c] += red[c + w];
            __syncthreads();
        }
        float nrm = fmaxf(sqrtf(red[0]), 1e-12f);
        gl[c] = v / nrm;
        __syncthreads();
        if (c < MID) {
            float s = 0.f;
            for (int k = 0; k < C; k++) s = fmaf(w1[c * C + k], gl[k], s);
            a[b * MID + c] = s;
        }
        {
            float s = 0.f;
            for (int k = 0; k < C; k++) s = fmaf(gl[k], Wco[k * C + c], s);
            gws[c] = s;
        }
        __syncthreads();
        float p0 = 0.f, p1 = 0.f, p2 = 0.f;
        for (int cc = 0; cc < C; cc++) {
            float wv = Wci[cc * C + c];
            float g = gws[cc];
            p0 = fmaf(g * wcd[3 * cc], wv, p0);
            p1 = fmaf(g * wcd[3 * cc + 1], wv, p1);
            p2 = fmaf(g * wcd[3 * cc + 2], wv, p2);
        }
        pv[b * 384 + c] = p0;
        pv[b * 384 + 128 + c] = p1;
        pv[b * 384 + 256 + c] = p2;
    }
}

// ------------------------------------------------ k_fused: outp[b][o][l] = A1@xC + AS@(sum of 4 nbrs) + Wproj@yd + Ws@silu + bp
// Persistent: grid 256 (1 block/CU), block = batch (bid&7), rows rg*4..rg*4+3 (1 row per iter).
// 16 waves = 8 l-groups x 2 o-halves; acc[4] (=16 regs) — total live kept under the empirical 64-reg unified cap.
// Neighbor-sum: AS@(vl+vr+vu+vd) — one MFMA group instead of four (13 K-chunks total).
__global__ __launch_bounds__(1024) __attribute__((amdgpu_waves_per_eu(4, 4)))
void k_fused(const ushort_t* __restrict__ xb,
             const ushort_t* __restrict__ Wf,
             const float* __restrict__ pv,
             const float* __restrict__ a,
             const float* __restrict__ b1,
             const float* __restrict__ pdw,
             const float* __restrict__ bp,
             float* __restrict__ outp,
             float* __restrict__ stats) {
    __shared__ ushort_t wlf[53248];           // 106,496 B, fragment-ordered weights
    __shared__ float spv[384];
    __shared__ float sdst[C];
    __shared__ float sdsq[C];
    const int tid = threadIdx.x;
    const int bid = blockIdx.x;
    const int b = bid & 7;                    // XCD k owns batch k
    const int rg = bid >> 3;                  // 0..31 row-group of 4

#pragma unroll
    for (int i = 0; i < 7; i++) {
        int idx = tid + i * 1024;
        if (idx < 6656) ((uint4*)wlf)[idx] = ((const uint4*)Wf)[idx];
    }
    if (tid < 384) spv[tid] = pv[b * 384 + tid];
    if (tid < C) { sdst[tid] = 0.f; sdsq[tid] = 0.f; }

    const int wave = tid >> 6, lane = tid & 63;
    const int half = wave & 1;                // o-half: [0,64) or [64,128)
    const int lg = wave >> 1;                 // l-group 0..7
    const int n = lane & 15, q = lane >> 4;
    const int xg = lg * 16 + n;
    const float dwt4 = pdw[0] * 0.25f;
    const size_t rb = (size_t)b * L;

    __syncthreads();

#define AF(slot, mt) (*(const s8v*)(wlf + ((((slot) * 8 + (half * 4 + mt)) * 64 + lane) * 8)))

#pragma unroll 1
    for (int iter = 0; iter < 4; iter++) {
        const int y = rg * 4 + iter;
        const int l = y * 128 + xg;

        const int rL = (l > 0) ? (l - 1) : -1;
        const int rR = (l < L - 1) ? (l + 1) : -1;
        const int rU = (y > 0) ? (l - 128) : ((xg > 0) ? (16256 + xg - 1) : -1);
        const int rD = (y < 127) ? (l + 128) : ((xg < 127) ? (xg + 1) : -1);
        const ushort_t* xrow = xb + (rb + l) * C;
        const ushort_t* prL = xb + (rb + ((rL >= 0) ? rL : 0)) * C;
        const ushort_t* prR = xb + (rb + ((rR >= 0) ? rR : 0)) * C;
        const ushort_t* prU = xb + (rb + ((rU >= 0) ? rU : 0)) * C;
        const ushort_t* prD = xb + (rb + ((rD >= 0) ? rD : 0)) * C;

        // ---- phase 1: s1 — one tap at a time (minimal liveness) ----
        float s1 = 0.f;
#pragma unroll
        for (int ks = 0; ks < 4; ks++) {
            const int c0 = ks * 32 + q * 8;
            {
                f8v xv = unp8(*(const s8v*)(xrow + c0));
                f8v p = ldf8(spv + 128 + c0);
#pragma unroll
                for (int j = 0; j < 8; j++) s1 = fmaf(p[j], xv[j], s1);
            }
            {
                f8v xv = unp8(*(const s8v*)(prL + c0));
                if (rL < 0) {
#pragma unroll
                    for (int j = 0; j < 8; j++) xv[j] = 0.f;
                }
                f8v p = ldf8(spv + c0);
#pragma unroll
                for (int j = 0; j < 8; j++) s1 = fmaf(p[j], xv[j], s1);
            }
            {
                f8v xv = unp8(*(const s8v*)(prR + c0));
                if (rR < 0) {
#pragma unroll
                    for (int j = 0; j < 8; j++) xv[j] = 0.f;
                }
                f8v p = ldf8(spv + 256 + c0);
#pragma unroll
                for (int j = 0; j < 8; j++) s1 = fmaf(p[j], xv[j], s1);
            }
        }
        s1 += __shfl_xor(s1, 16);
        s1 += __shfl_xor(s1, 32);

        f4v acc[4];
#pragma unroll
        for (int i = 0; i < 4; i++) acc[i] = (f4v){0.f, 0.f, 0.f, 0.f};

        // ---- phase 2: silu chunk, fs dies immediately ----
        {
            f8v av = ldf8(a + b * MID + q * 8);
            f8v bv = ldf8(b1 + q * 8);
            s8v fs;
#pragma unroll
            for (int j = 0; j < 8; j++) {
                float pre = fmaf(av[j], s1, bv[j]);
                fs[j] = (short)f2bf(pre / (1.f + __expf(-pre)));
            }
#pragma unroll
            for (int mt = 0; mt < 4; mt++)
                acc[mt] = __builtin_amdgcn_mfma_f32_16x16x32_bf16(AF(12, mt), fs, acc[mt], 0, 0, 0);
        }

        // ---- phase 3: per-ks {A1@vc; neighbor-sum -> AS; pairwise yd -> Wproj} ----
#pragma unroll
        for (int ks = 0; ks < 4; ks++) {
            const int c0 = ks * 32 + q * 8;
            s8v vc = *(const s8v*)(xrow + c0);
#pragma unroll
            for (int mt = 0; mt < 4; mt++)
                acc[mt] = __builtin_amdgcn_mfma_f32_16x16x32_bf16(AF(ks, mt), vc, acc[mt], 0, 0, 0);
            f8v xc = unp8(vc);

            f8v sum, d8;
            {   // L/R pair
                s8v vl = *(const s8v*)(prL + c0);
                s8v vr = *(const s8v*)(prR + c0);
                f8v xl = unp8(vl);
                f8v xr = unp8(vr);
                if (rL < 0) {
#pragma unroll
                    for (int j = 0; j < 8; j++) xl[j] = 0.f;
                }
                if (rR < 0) {
#pragma unroll
                    for (int j = 0; j < 8; j++) xr[j] = 0.f;
                }
                sum = xl + xr;
                f8v a1 = (xg > 0) ? xl : xr;      // reflect sL
                f8v a2 = (xg < 127) ? xr : xl;    // reflect sR
#pragma unroll
                for (int j = 0; j < 8; j++)
                    d8[j] = fabsf(xc[j] - a1[j]) + fabsf(xc[j] - a2[j]);
            }
            {   // U/D pair
                s8v vu = *(const s8v*)(prU + c0);
                s8v vd = *(const s8v*)(prD + c0);
                f8v xu = unp8(vu);
                f8v xd = unp8(vd);
                if (rU < 0) {
#pragma unroll
                    for (int j = 0; j < 8; j++) xu[j] = 0.f;
                }
                if (rD < 0) {
#pragma unroll
                    for (int j = 0; j < 8; j++) xd[j] = 0.f;
                }
                sum = sum + (xu + xd);
                f8v a3 = (y > 0) ? xu : xd;       // reflect sU
                f8v a4 = (y < 127) ? xd : xu;     // reflect sD
#pragma unroll
                for (int j = 0; j < 8; j++)
                    d8[j] += fabsf(xc[j] - a3[j]) + fabsf(xc[j] - a4[j]);
            }
            {
                s8v vs = pk8(sum);
#pragma unroll
                for (int mt = 0; mt < 4; mt++)
                    acc[mt] = __builtin_amdgcn_mfma_f32_16x16x32_bf16(AF(4 + ks, mt), vs, acc[mt], 0, 0, 0);
            }
            {
                s8v vy;
#pragma unroll
                for (int j = 0; j < 8; j++) vy[j] = (short)f2bf(fmaf(dwt4, d8[j], xc[j]));
#pragma unroll
                for (int mt = 0; mt < 4; mt++)
                    acc[mt] = __builtin_amdgcn_mfma_f32_16x16x32_bf16(AF(8 + ks, mt), vy, acc[mt], 0, 0, 0);
            }
        }

        // ---- epilogue: bias + store + BN partial stats ----
#pragma unroll
        for (int mt = 0; mt < 4; mt++) {
            const int o0 = (half * 4 + mt) * 16 + q * 4;
            float4 bv4 = *(const float4*)(bp + o0);
#pragma unroll
            for (int i = 0; i < 4; i++) {
                float bai = (i == 0) ? bv4.x : (i == 1) ? bv4.y : (i == 2) ? bv4.z : bv4.w;
                float v = acc[mt][i] + bai;
                outp[((size_t)(b * C + o0 + i)) * L + l] = v;
                float s = v, sq = v * v;
                s += __shfl_xor(s, 1); sq += __shfl_xor(sq, 1);
                s += __shfl_xor(s, 2); sq += __shfl_xor(sq, 2);
                s += __shfl_xor(s, 4); sq += __shfl_xor(sq, 4);
                s += __shfl_xor(s, 8); sq += __shfl_xor(sq, 8);
                if (n == 0) {
                    atomicAdd(&sdst[o0 + i], s);
                    atomicAdd(&sdsq[o0 + i], sq);
                }
            }
        }
    }

#undef AF

    __syncthreads();
    if (tid < C) {
        atomicAdd(&stats[tid], sdst[tid]);
        atomicAdd(&stats[C + tid], sdsq[tid]);
    }
}

// ------------------------------------------------ k_bnapply: inline finalize + scale/shift
__global__ __launch_bounds__(256) void k_bnapply(float* __restrict__ outp,
                                                 const float* __restrict__ stats,
                                                 const float* __restrict__ gamma,
                                                 const float* __restrict__ beta) {
    int bo = blockIdx.x;
    int o = bo & (C - 1);
    float nn = (float)NBL;
    float mu = stats[o] / nn;
    float var = stats[C + o] / nn - mu * mu;
    float sc = gamma[o] * rsqrtf(var + 1e-5f);
    float sh = fmaf(-mu, sc, beta[o]);
    float4* p = (float4*)(outp + (size_t)bo * L);
    for (int i = threadIdx.x; i < L / 4; i += 256) {
        float4 v = p[i];
        v.x = fmaf(v.x, sc, sh);
        v.y = fmaf(v.y, sc, sh);
        v.z = fmaf(v.z, sc, sh);
        v.w = fmaf(v.w, sc, sh);
        p[i] = v;
    }
}

// ------------------------------------------------ launch
extern "C" void kernel_launch(void* const* d_in, const int* in_sizes, int n_in,
                              void* d_out, int out_size, void* d_ws, size_t ws_size,
                              hipStream_t stream) {
    const float* x = (const float*)d_in[0];
    const float* Win = (const float*)d_in[1];
    const float* wds = (const float*)d_in[2];
    const float* Wout = (const float*)d_in[3];
    const float* Wci = (const float*)d_in[4];
    const float* wcd = (const float*)d_in[5];
    const float* Wco = (const float*)d_in[6];
    const float* w1 = (const float*)d_in[7];
    const float* b1 = (const float*)d_in[8];
    const float* w2 = (const float*)d_in[9];
    const float* b2 = (const float*)d_in[10];
    const float* pdw = (const float*)d_in[11];
    const float* gamma = (const float*)d_in[12];
    const float* beta = (const float*)d_in[13];
    const float* Wproj = (const float*)d_in[14];

    char* wsb = (char*)d_ws;
    ushort_t* xb = (ushort_t*)wsb;                       // 33,554,432 B
    ushort_t* Wf = (ushort_t*)(wsb + 33554432);          // 106,496 B
    char* S = wsb + 176160768;
    float* gap  = (float*)(S + 0);        // 1024 B
    float* stats= (float*)(S + 4096);     // 1024 B
    float* a    = (float*)(S + 6144);     // 1024 B
    float* bp   = (float*)(S + 8192);     // 512 B
    float* pv   = (float*)(S + 12288);    // 12,288 B
    float* outp = (float*)d_out;

    hipMemsetAsync(S, 0, 5120, stream);  // gap + stats
    k_cvt<<<2048, 256, 0, stream>>>(x, xb, gap);
    k_prep<<<136, 128, 0, stream>>>(Win, Wproj, Wout, w2, b2, wds,
                                    gap, w1, Wco, wcd, Wci, Wf, bp, a, pv);
    k_fused<<<256, 1024, 0, stream>>>(xb, Wf, pv, a, b1, pdw, bp, outp, stats);
    k_bnapply<<<1024, 256, 0, stream>>>(outp, stats, gamma, beta);
}

// Round 9
// 329.194 us; speedup vs baseline: 2.2227x; 2.2227x over previous
//
#include <hip/hip_runtime.h>
#include <hip/hip_bf16.h>

#define C 128
#define L 16384
#define B 8
#define MID 32
#define NBL (B * L)

typedef unsigned short ushort_t;
typedef __attribute__((ext_vector_type(8))) short s8v;   // 8 bf16
typedef __attribute__((ext_vector_type(4))) float f4v;   // 4 fp32
typedef __attribute__((ext_vector_type(8))) float f8v;   // 8 fp32

__device__ __forceinline__ unsigned short f2bf(float f) {
    union { float f; unsigned int u; } a; a.f = f;
    unsigned int u = a.u;
    return (unsigned short)((u + 0x7fffu + ((u >> 16) & 1u)) >> 16);
}

// value-style helpers: no address-taken locals
__device__ __forceinline__ f8v unp8(s8v v) {
    f8v f;
#pragma unroll
    for (int j = 0; j < 8; j++) f[j] = __uint_as_float(((unsigned int)(unsigned short)v[j]) << 16);
    return f;
}

__device__ __forceinline__ f8v ldf8(const float* p) {
    float4 a = *(const float4*)p;
    float4 b = *(const float4*)(p + 4);
    f8v f;
    f[0] = a.x; f[1] = a.y; f[2] = a.z; f[3] = a.w;
    f[4] = b.x; f[5] = b.y; f[6] = b.z; f[7] = b.w;
    return f;
}

// fragment-order index for staged weights: slot in [0,13), o = out channel row, w = col within slot's 32
__device__ __forceinline__ int widx(int slot, int o, int w) {
    return ((slot * 8 + (o >> 4)) * 64 + (w >> 3) * 16 + (o & 15)) * 8 + (w & 7);
}

// ------------------------------------------------ k_cvt: x fp32 [b][c][l] -> xb bf16 [b][l][c], + gap sums
// Coalesced reads: 8 passes of 16 c-rows x 64 l floats, lane-contiguous float4. (verified in R7)
__global__ __launch_bounds__(256) void k_cvt(const float* __restrict__ x,
                                             ushort_t* __restrict__ xb,
                                             float* __restrict__ gap) {
    __shared__ float xs[64][129];             // [l][c]
    const int bid = blockIdx.x;
    const int b = bid >> 8;
    const int l0 = (bid & 255) * 64;
    const int tid = threadIdx.x;
    const int rr = tid >> 4;                  // row within pass (0..15)
    const int col = (tid & 15) * 4;           // l within tile (0..60)
#pragma unroll
    for (int pass = 0; pass < 8; pass++) {
        const int c = pass * 16 + rr;
        float4 v = *(const float4*)(x + ((size_t)(b * C + c)) * L + l0 + col);
        xs[col + 0][c] = v.x; xs[col + 1][c] = v.y;
        xs[col + 2][c] = v.z; xs[col + 3][c] = v.w;
    }
    __syncthreads();
    // gap partial sums (from LDS)
    {
        const int c = tid >> 1, h = tid & 1;
        float s = 0.f;
#pragma unroll
        for (int k = 0; k < 32; k++) s += xs[h * 32 + k][c];
        s += __shfl_xor(s, 1);
        if (h == 0) atomicAdd(&gap[b * C + c], s);
    }
    // pack + coalesced write of [l][c] bf16
    const int l = tid & 63, quarter = tid >> 6, cb = quarter * 32;
    union { ushort_t hh[32]; uint4 qv[4]; } u;
#pragma unroll
    for (int k = 0; k < 32; k++) u.hh[k] = f2bf(xs[l][cb + k]);
    uint4* dst = (uint4*)(xb + ((size_t)(b * L + l0 + l)) * C + cb);
#pragma unroll
    for (int k = 0; k < 4; k++) dst[k] = u.qv[k];
}

// ------------------------------------------------ k_prep: merged weight-compose (bid<128) + per-batch gap work (bid>=128)
__global__ __launch_bounds__(128) void k_prep(const float* __restrict__ Win,
                                              const float* __restrict__ Wproj,
                                              const float* __restrict__ Wout,
                                              const float* __restrict__ w2,
                                              const float* __restrict__ b2,
                                              const float* __restrict__ wds,
                                              const float* __restrict__ gap,
                                              const float* __restrict__ w1,
                                              const float* __restrict__ Wco,
                                              const float* __restrict__ wcd,
                                              const float* __restrict__ Wci,
                                              ushort_t* __restrict__ Wf,
                                              float* __restrict__ bp,
                                              float* __restrict__ a,
                                              float* __restrict__ pv) {
    const int bid = blockIdx.x;
    const int c = threadIdx.x;
    if (bid < 128) {
        const int o = bid;
        __shared__ float pr[C];
        __shared__ float wct[C];
        pr[c] = Wproj[o * C + c];
        __syncthreads();
        {
            float s = 0.f;
            for (int k = 0; k < C; k++) s = fmaf(pr[k], Wout[k * C + c], s);
            wct[c] = s;
        }
        __syncthreads();
        float a1 = 0.f, as = 0.f;
        for (int cc = 0; cc < C; cc++) {
            float w = wct[cc];
            float win = Win[cc * C + c];
            a1 = fmaf(w * wds[3 * cc + 1], win, a1);
            as = fmaf(w * (0.25f * (wds[3 * cc] + wds[3 * cc + 2])), win, as);
        }
        const int slot = c >> 5, wi = c & 31;
        Wf[widx(slot, o, wi)] = f2bf(a1);
        Wf[widx(4 + slot, o, wi)] = f2bf(as);
        Wf[widx(8 + slot, o, wi)] = f2bf(pr[c]);
        if (c < MID) {
            float s2 = 0.f;
            for (int k = 0; k < C; k++) s2 = fmaf(pr[k], w2[k * MID + c], s2);
            Wf[widx(12, o, c)] = f2bf(s2);
        }
        if (c == 0) {
            float s3 = 0.f;
            for (int k = 0; k < C; k++) s3 = fmaf(pr[k], b2[k], s3);
            bp[o] = s3;
        }
    } else {
        const int b = bid - 128;
        __shared__ float gl[C];
        __shared__ float red[C];
        __shared__ float gws[C];
        float v = gap[b * C + c] * (1.f / (float)L);
        red[c] = v * v;
        __syncthreads();
        for (int w = 64; w > 0; w >>= 1) {
            if (c < w) red[c] += red[c + w];
            __syncthreads();
        }
        float nrm = fmaxf(sqrtf(red[0]), 1e-12f);
        gl[c] = v / nrm;
        __syncthreads();
        if (c < MID) {
            float s = 0.f;
            for (int k = 0; k < C; k++) s = fmaf(w1[c * C + k], gl[k], s);
            a[b * MID + c] = s;
        }
        {
            float s = 0.f;
            for (int k = 0; k < C; k++) s = fmaf(gl[k], Wco[k * C + c], s);
            gws[c] = s;
        }
        __syncthreads();
        float p0 = 0.f, p1 = 0.f, p2 = 0.f;
        for (int cc = 0; cc < C; cc++) {
            float wv = Wci[cc * C + c];
            float g = gws[cc];
            p0 = fmaf(g * wcd[3 * cc], wv, p0);
            p1 = fmaf(g * wcd[3 * cc + 1], wv, p1);
            p2 = fmaf(g * wcd[3 * cc + 2], wv, p2);
        }
        pv[b * 384 + c] = p0;
        pv[b * 384 + 128 + c] = p1;
        pv[b * 384 + 256 + c] = p2;
    }
}

// ------------------------------------------------ k_fused: outp[b][o][l] = A1@xC + AS@(4 nbrs) + Wproj@yd + Ws@silu + bp
// R4-proven structure: NON-persistent, grid 1024 = 8 b * 128 y (one row per block); 1024 threads = 16 waves
// = 8 l-groups x 2 o-halves; acc[4]; phased gen (only acc survives between phases). Epilogue adds BN stats.
__global__ __launch_bounds__(1024) __attribute__((amdgpu_waves_per_eu(4, 4)))
void k_fused(const ushort_t* __restrict__ xb,
             const ushort_t* __restrict__ Wf,
             const float* __restrict__ pv,
             const float* __restrict__ a,
             const float* __restrict__ b1,
             const float* __restrict__ pdw,
             const float* __restrict__ bp,
             float* __restrict__ outp,
             float* __restrict__ stats) {
    __shared__ ushort_t wlf[53248];           // 106,496 B, fragment-ordered weights
    __shared__ float sdst[C];
    __shared__ float sdsq[C];
    const int tid = threadIdx.x;
    int bid = blockIdx.x;
    bid = (bid & 7) * 128 + (bid >> 3);       // bijective XCD swizzle: XCD k owns batch k
    const int b = bid >> 7;
    const int y = bid & 127;

    // stage Wf: 6656 uint4 over 1024 threads; zero LDS stats
#pragma unroll
    for (int i = 0; i < 7; i++) {
        int idx = tid + i * 1024;
        if (idx < 6656) ((uint4*)wlf)[idx] = ((const uint4*)Wf)[idx];
    }
    if (tid < C) { sdst[tid] = 0.f; sdsq[tid] = 0.f; }

    const int wave = tid >> 6, lane = tid & 63;
    const int half = wave & 1;                // o-half
    const int lg = wave >> 1;                 // l-group within the row
    const int n = lane & 15, q = lane >> 4;
    const int xg = lg * 16 + n;
    const int l = y * 128 + xg;
    const size_t rb = (size_t)b * L;

    const int rL = (l > 0) ? (l - 1) : -1;
    const int rR = (l < L - 1) ? (l + 1) : -1;
    const int rU = (y > 0) ? (l - 128) : ((xg > 0) ? (16256 + xg - 1) : -1);
    const int rD = (y < 127) ? (l + 128) : ((xg < 127) ? (xg + 1) : -1);
    const ushort_t* xrow = xb + (rb + l) * C;
    const ushort_t* prL = xb + (rb + ((rL >= 0) ? rL : 0)) * C;
    const ushort_t* prR = xb + (rb + ((rR >= 0) ? rR : 0)) * C;
    const ushort_t* prU = xb + (rb + ((rU >= 0) ? rU : 0)) * C;
    const ushort_t* prD = xb + (rb + ((rD >= 0) ? rD : 0)) * C;

    const float dwt4 = pdw[0] * 0.25f;

    // ---- phase 1: s1 — one tap at a time (minimal liveness) ----
    float s1 = 0.f;
#pragma unroll
    for (int ks = 0; ks < 4; ks++) {
        const int c0 = ks * 32 + q * 8;
        {
            f8v xv = unp8(*(const s8v*)(xrow + c0));
            f8v p = ldf8(pv + b * 384 + 128 + c0);
#pragma unroll
            for (int j = 0; j < 8; j++) s1 = fmaf(p[j], xv[j], s1);
        }
        {
            f8v xv = unp8(*(const s8v*)(prL + c0));
            if (rL < 0) {
#pragma unroll
                for (int j = 0; j < 8; j++) xv[j] = 0.f;
            }
            f8v p = ldf8(pv + b * 384 + c0);
#pragma unroll
            for (int j = 0; j < 8; j++) s1 = fmaf(p[j], xv[j], s1);
        }
        {
            f8v xv = unp8(*(const s8v*)(prR + c0));
            if (rR < 0) {
#pragma unroll
                for (int j = 0; j < 8; j++) xv[j] = 0.f;
            }
            f8v p = ldf8(pv + b * 384 + 256 + c0);
#pragma unroll
            for (int j = 0; j < 8; j++) s1 = fmaf(p[j], xv[j], s1);
        }
    }
    s1 += __shfl_xor(s1, 16);
    s1 += __shfl_xor(s1, 32);

    s8v fs;
    {
        f8v av = ldf8(a + b * MID + q * 8);
        f8v bv = ldf8(b1 + q * 8);
#pragma unroll
        for (int j = 0; j < 8; j++) {
            float pre = fmaf(av[j], s1, bv[j]);
            fs[j] = (short)f2bf(pre / (1.f + __expf(-pre)));
        }
    }

    f4v acc[4];
#pragma unroll
    for (int i = 0; i < 4; i++) acc[i] = (f4v){0.f, 0.f, 0.f, 0.f};

    __syncthreads();

#define AF(slot, mtg) (*(const s8v*)(wlf + ((((slot) * 8 + (mtg)) * 64 + lane) * 8)))

    // ---- phase 2: slot 12 (silu) — fs dies here ----
#pragma unroll
    for (int mt = 0; mt < 4; mt++)
        acc[mt] = __builtin_amdgcn_mfma_f32_16x16x32_bf16(AF(12, half * 4 + mt), fs, acc[mt], 0, 0, 0);

    // ---- phase 3: slots 4-7, AS @ zero-padded stencil neighbors (direct load->MFMA) ----
#pragma unroll
    for (int t = 0; t < 4; t++) {
        const int r = (t == 0) ? rL : (t == 1) ? rR : (t == 2) ? rU : rD;
        const ushort_t* prow = (t == 0) ? prL : (t == 1) ? prR : (t == 2) ? prU : prD;
#pragma unroll
        for (int ks = 0; ks < 4; ks++) {
            s8v v = *(const s8v*)(prow + ks * 32 + q * 8);
            if (r < 0) v = (s8v){0, 0, 0, 0, 0, 0, 0, 0};
#pragma unroll
            for (int mt = 0; mt < 4; mt++)
                acc[mt] = __builtin_amdgcn_mfma_f32_16x16x32_bf16(AF(4 + ks, half * 4 + mt), v, acc[mt], 0, 0, 0);
        }
    }

    // ---- phase 4: per-ks A1 @ xC then Wproj @ yd (incremental diff; nothing survives the ks-iter) ----
#pragma unroll
    for (int ks = 0; ks < 4; ks++) {
        const int c0 = ks * 32 + q * 8;
        s8v vc = *(const s8v*)(xrow + c0);
#pragma unroll
        for (int mt = 0; mt < 4; mt++)
            acc[mt] = __builtin_amdgcn_mfma_f32_16x16x32_bf16(AF(ks, half * 4 + mt), vc, acc[mt], 0, 0, 0);
        f8v xc = unp8(vc);
        f8v d8;
        {   // reflect sL: interior = rL row; boundary xg==0 -> l+1 = rR row
            f8v t1 = unp8(*(const s8v*)(((xg > 0) ? prL : prR) + c0));
#pragma unroll
            for (int j = 0; j < 8; j++) d8[j] = fabsf(xc[j] - t1[j]);
        }
        {   // reflect sR
            f8v t1 = unp8(*(const s8v*)(((xg < 127) ? prR : prL) + c0));
#pragma unroll
            for (int j = 0; j < 8; j++) d8[j] += fabsf(xc[j] - t1[j]);
        }
        {   // reflect sU: interior = l-128 (= rU row when y>0); boundary y==0 -> l+128 = rD row
            f8v t1 = unp8(*(const s8v*)(((y > 0) ? prU : prD) + c0));
#pragma unroll
            for (int j = 0; j < 8; j++) d8[j] += fabsf(xc[j] - t1[j]);
        }
        {   // reflect sD
            f8v t1 = unp8(*(const s8v*)(((y < 127) ? prD : prU) + c0));
#pragma unroll
            for (int j = 0; j < 8; j++) d8[j] += fabsf(xc[j] - t1[j]);
        }
        s8v vy;
#pragma unroll
        for (int j = 0; j < 8; j++) vy[j] = (short)f2bf(fmaf(dwt4, d8[j], xc[j]));
#pragma unroll
        for (int mt = 0; mt < 4; mt++)
            acc[mt] = __builtin_amdgcn_mfma_f32_16x16x32_bf16(AF(8 + ks, half * 4 + mt), vy, acc[mt], 0, 0, 0);
    }

#undef AF

    // ---- epilogue: bias + store to outp [b][o][l] + BN partial stats ----
#pragma unroll
    for (int mt = 0; mt < 4; mt++) {
        const int o0 = (half * 4 + mt) * 16 + q * 4;
        float4 bv4 = *(const float4*)(bp + o0);
#pragma unroll
        for (int i = 0; i < 4; i++) {
            float bai = (i == 0) ? bv4.x : (i == 1) ? bv4.y : (i == 2) ? bv4.z : bv4.w;
            float v = acc[mt][i] + bai;
            outp[((size_t)(b * C + o0 + i)) * L + l] = v;
            float s = v, sq = v * v;
            s += __shfl_xor(s, 1); sq += __shfl_xor(sq, 1);
            s += __shfl_xor(s, 2); sq += __shfl_xor(sq, 2);
            s += __shfl_xor(s, 4); sq += __shfl_xor(sq, 4);
            s += __shfl_xor(s, 8); sq += __shfl_xor(sq, 8);
            if (n == 0) {
                atomicAdd(&sdst[o0 + i], s);
                atomicAdd(&sdsq[o0 + i], sq);
            }
        }
    }
    __syncthreads();
    if (tid < C) {
        atomicAdd(&stats[tid], sdst[tid]);
        atomicAdd(&stats[C + tid], sdsq[tid]);
    }
}

// ------------------------------------------------ k_bnapply: inline finalize + in-place scale/shift
__global__ __launch_bounds__(256) void k_bnapply(float* __restrict__ outp,
                                                 const float* __restrict__ stats,
                                                 const float* __restrict__ gamma,
                                                 const float* __restrict__ beta) {
    int bo = blockIdx.x;
    int o = bo & (C - 1);
    float nn = (float)NBL;
    float mu = stats[o] / nn;
    float var = stats[C + o] / nn - mu * mu;
    float sc = gamma[o] * rsqrtf(var + 1e-5f);
    float sh = fmaf(-mu, sc, beta[o]);
    float4* p = (float4*)(outp + (size_t)bo * L);
    for (int i = threadIdx.x; i < L / 4; i += 256) {
        float4 v = p[i];
        v.x = fmaf(v.x, sc, sh);
        v.y = fmaf(v.y, sc, sh);
        v.z = fmaf(v.z, sc, sh);
        v.w = fmaf(v.w, sc, sh);
        p[i] = v;
    }
}

// ------------------------------------------------ launch
extern "C" void kernel_launch(void* const* d_in, const int* in_sizes, int n_in,
                              void* d_out, int out_size, void* d_ws, size_t ws_size,
                              hipStream_t stream) {
    const float* x = (const float*)d_in[0];
    const float* Win = (const float*)d_in[1];
    const float* wds = (const float*)d_in[2];
    const float* Wout = (const float*)d_in[3];
    const float* Wci = (const float*)d_in[4];
    const float* wcd = (const float*)d_in[5];
    const float* Wco = (const float*)d_in[6];
    const float* w1 = (const float*)d_in[7];
    const float* b1 = (const float*)d_in[8];
    const float* w2 = (const float*)d_in[9];
    const float* b2 = (const float*)d_in[10];
    const float* pdw = (const float*)d_in[11];
    const float* gamma = (const float*)d_in[12];
    const float* beta = (const float*)d_in[13];
    const float* Wproj = (const float*)d_in[14];

    char* wsb = (char*)d_ws;
    ushort_t* xb = (ushort_t*)wsb;                       // 33,554,432 B
    ushort_t* Wf = (ushort_t*)(wsb + 33554432);          // 106,496 B
    char* S = wsb + 176160768;
    float* gap  = (float*)(S + 0);        // 1024 B
    float* stats= (float*)(S + 4096);     // 1024 B
    float* a    = (float*)(S + 6144);     // 1024 B
    float* bp   = (float*)(S + 8192);     // 512 B
    float* pv   = (float*)(S + 12288);    // 12,288 B
    float* outp = (float*)d_out;

    hipMemsetAsync(S, 0, 5120, stream);  // gap + stats
    k_cvt<<<2048, 256, 0, stream>>>(x, xb, gap);
    k_prep<<<136, 128, 0, stream>>>(Win, Wproj, Wout, w2, b2, wds,
                                    gap, w1, Wco, wcd, Wci, Wf, bp, a, pv);
    k_fused<<<1024, 1024, 0, stream>>>(xb, Wf, pv, a, b1, pdw, bp, outp, stats);
    k_bnapply<<<1024, 256, 0, stream>>>(outp, stats, gamma, beta);
}